// Round 1
// 440.668 us; speedup vs baseline: 2.2832x; 2.2832x over previous
//
#include <hip/hip_runtime.h>
#include <math.h>

#define B_ 2
#define T_ 256
#define DM_ 512
#define H_ 8
#define DH_ 64
#define HID_ 128
#define GH_ 64
#define NMEM_ 32768
#define TOPK_ 32
#define BT_ (B_*T_)      // 512
#define HD_ (H_*DH_)     // 512
#define SELC_ 8192
#define NCHUNK_ (NMEM_/SELC_)  // 4
#define TT_ 16           // t-tile for fused attention

// ---------------- generic tiled fp32 GEMM: C = act(A @ W + bias) ----------------
// W/C selected by blockIdx.z (lets Q/K/V run as one launch). act: 0=none, 1=tanh-gelu
__global__ __launch_bounds__(256) void awm_proj_kernel(
    const float* __restrict__ A,
    const float* __restrict__ W0, const float* __restrict__ W1, const float* __restrict__ W2,
    const float* __restrict__ bias,
    float* __restrict__ C0, float* __restrict__ C1, float* __restrict__ C2,
    int M, int N, int K, int act) {
    (void)M;
    const float* W = (blockIdx.z == 0) ? W0 : (blockIdx.z == 1 ? W1 : W2);
    float* C = (blockIdx.z == 0) ? C0 : (blockIdx.z == 1 ? C1 : C2);
    __shared__ float As[16][68];
    __shared__ float Bs[16][68];
    int bm = blockIdx.y * 64, bn = blockIdx.x * 64;
    int tid = threadIdx.x;
    int tm = (tid >> 4) * 4, tn = (tid & 15) * 4;
    float acc[4][4] = {};
    for (int k0 = 0; k0 < K; k0 += 16) {
        {
            int i4 = tid * 4;
            int m = i4 >> 4, kk = i4 & 15;
            float4 a = *(const float4*)&A[(size_t)(bm + m) * K + k0 + kk];
            As[kk+0][m] = a.x; As[kk+1][m] = a.y; As[kk+2][m] = a.z; As[kk+3][m] = a.w;
            int kb = i4 >> 6, n = i4 & 63;
            *(float4*)&Bs[kb][n] = *(const float4*)&W[(size_t)(k0 + kb) * N + bn + n];
        }
        __syncthreads();
#pragma unroll
        for (int kk = 0; kk < 16; ++kk) {
            float4 a4 = *(const float4*)&As[kk][tm];
            float4 b4 = *(const float4*)&Bs[kk][tn];
            float av[4] = {a4.x, a4.y, a4.z, a4.w};
            float bv[4] = {b4.x, b4.y, b4.z, b4.w};
#pragma unroll
            for (int x = 0; x < 4; ++x)
#pragma unroll
                for (int y = 0; y < 4; ++y) acc[x][y] += av[x] * bv[y];
        }
        __syncthreads();
    }
#pragma unroll
    for (int x = 0; x < 4; ++x) {
        float vv[4];
#pragma unroll
        for (int y = 0; y < 4; ++y) {
            float v = acc[x][y] + (bias ? bias[bn + tn + y] : 0.f);
            if (act == 1) {
                float u = 0.7978845608028654f * (v + 0.044715f * v * v * v);
                v = 0.5f * v * (1.f + tanhf(u));
            }
            vv[y] = v;
        }
        float4 r; r.x = vv[0]; r.y = vv[1]; r.z = vv[2]; r.w = vv[3];
        *(float4*)&C[(size_t)(bm + tm + x) * N + bn + tn] = r;
    }
}

// ---------------- gates = sigmoid(g1 @ Wg2 + bg2) ----------------
__global__ void awm_gates_kernel(const float* __restrict__ g1, const float* __restrict__ Wg2,
                                 const float* __restrict__ bg2, float* __restrict__ gates) {
    int i = blockIdx.x * 256 + threadIdx.x;  // r*H + h
    if (i >= BT_ * H_) return;
    int r = i / H_, h = i % H_;
    float acc = bg2[h];
    for (int j = 0; j < GH_; ++j) acc += g1[r * GH_ + j] * Wg2[j * H_ + h];
    gates[i] = 1.f / (1.f + expf(-acc));
}

// ---------------- q_for_mem: mean over heads ----------------
__global__ void awm_qmean_kernel(const float* __restrict__ q_flat, float* __restrict__ qm) {
    int i = blockIdx.x * 256 + threadIdx.x;  // r*DH + d
    if (i >= BT_ * DH_) return;
    int r = i / DH_, d = i % DH_;
    float acc = 0.f;
#pragma unroll
    for (int h = 0; h < H_; ++h) acc += q_flat[r * HD_ + h * DH_ + d];
    qm[i] = acc * 0.125f;
}

// ---------------- sel chunk GEMM: selc[r][n] = qm[r] . mem_keys[chunk0+n] ----------------
__global__ __launch_bounds__(256) void awm_selgemm_kernel(
    const float* __restrict__ qm, const float* __restrict__ mkeys,
    float* __restrict__ selc, int chunk0) {
    __shared__ float Qs[64][68];    // [d][m]
    __shared__ float Ks[64][132];   // [d][n]
    int bn = blockIdx.x * 128;
    int bm = blockIdx.y * 64;
    int tid = threadIdx.x;
#pragma unroll
    for (int p = 0; p < 4; ++p) {
        int i4 = tid * 4 + p * 1024;
        int m = i4 >> 6, d = i4 & 63;
        float4 a = *(const float4*)&qm[(size_t)(bm + m) * DH_ + d];
        Qs[d+0][m] = a.x; Qs[d+1][m] = a.y; Qs[d+2][m] = a.z; Qs[d+3][m] = a.w;
    }
#pragma unroll
    for (int p = 0; p < 8; ++p) {
        int i4 = tid * 4 + p * 1024;
        int n = i4 >> 6, d = i4 & 63;
        float4 a = *(const float4*)&mkeys[(size_t)(chunk0 + bn + n) * DH_ + d];
        Ks[d+0][n] = a.x; Ks[d+1][n] = a.y; Ks[d+2][n] = a.z; Ks[d+3][n] = a.w;
    }
    __syncthreads();
    int tm = (tid >> 4) * 4;
    int tn = (tid & 15) * 8;
    float acc[4][8] = {};
#pragma unroll 8
    for (int d = 0; d < 64; ++d) {
        float4 a4 = *(const float4*)&Qs[d][tm];
        float4 b0 = *(const float4*)&Ks[d][tn];
        float4 b1 = *(const float4*)&Ks[d][tn + 4];
        float av[4] = {a4.x, a4.y, a4.z, a4.w};
        float bv[8] = {b0.x, b0.y, b0.z, b0.w, b1.x, b1.y, b1.z, b1.w};
#pragma unroll
        for (int x = 0; x < 4; ++x)
#pragma unroll
            for (int y = 0; y < 8; ++y) acc[x][y] += av[x] * bv[y];
    }
#pragma unroll
    for (int x = 0; x < 4; ++x) {
        float* cp = &selc[(size_t)(bm + tm + x) * SELC_ + bn + tn];
        float4 r0, r1;
        r0.x = acc[x][0]; r0.y = acc[x][1]; r0.z = acc[x][2]; r0.w = acc[x][3];
        r1.x = acc[x][4]; r1.y = acc[x][5]; r1.z = acc[x][6]; r1.w = acc[x][7];
        *(float4*)cp = r0; *(float4*)(cp + 4) = r1;
    }
}

// ---------------- per-chunk top-32: register-cached maxima + owner-only rescan ----------------
__global__ __launch_bounds__(256) void awm_seltop_kernel(
    const float* __restrict__ selc, float* __restrict__ cand_val,
    int* __restrict__ cand_idx, int chunk) {
    int r = blockIdx.x;
    int tid = threadIdx.x;  // 256
    __shared__ float sv[SELC_];
    __shared__ float wv_s[4];
    __shared__ int wi_s[4];
    __shared__ int win_s;
    // stage (coalesced)
    for (int k = 0; k < SELC_ / 256; ++k) {
        int i = tid + k * 256;
        sv[i] = selc[(size_t)r * SELC_ + i];
    }
    __syncthreads();
    // each thread owns 32 contiguous slots; cache local argmax in regs
    int base = tid * 32;
    float lv = -INFINITY; int li = -1;
#pragma unroll
    for (int k = 0; k < 32; k += 4) {
        float4 q = *(const float4*)&sv[base + k];
        if (q.x > lv) { lv = q.x; li = base + k; }
        if (q.y > lv) { lv = q.y; li = base + k + 1; }
        if (q.z > lv) { lv = q.z; li = base + k + 2; }
        if (q.w > lv) { lv = q.w; li = base + k + 3; }
    }
    int wid = tid >> 6, lane = tid & 63;
    for (int it = 0; it < TOPK_; ++it) {
        float v = lv; int ix = li;
#pragma unroll
        for (int off = 32; off > 0; off >>= 1) {
            float ov = __shfl_xor(v, off);
            int oi = __shfl_xor(ix, off);
            if (ov > v || (ov == v && (unsigned)oi < (unsigned)ix)) { v = ov; ix = oi; }
        }
        if (lane == 0) { wv_s[wid] = v; wi_s[wid] = ix; }
        __syncthreads();
        if (tid == 0) {
            float bv = wv_s[0]; int bi = wi_s[0];
#pragma unroll
            for (int w2 = 1; w2 < 4; ++w2) {
                float ov = wv_s[w2]; int oi = wi_s[w2];
                if (ov > bv || (ov == bv && (unsigned)oi < (unsigned)bi)) { bv = ov; bi = oi; }
            }
            cand_val[r * 128 + chunk * TOPK_ + it] = bv;
            cand_idx[r * 128 + chunk * TOPK_ + it] = chunk * SELC_ + bi;
            win_s = bi;
        }
        __syncthreads();
        int wn = win_s;
        if ((wn >> 5) == tid) {   // owner invalidates + rescans its 32
            sv[wn] = -INFINITY;
            lv = -INFINITY; li = -1;
#pragma unroll
            for (int k = 0; k < 32; k += 4) {
                float4 q = *(const float4*)&sv[base + k];
                if (q.x > lv) { lv = q.x; li = base + k; }
                if (q.y > lv) { lv = q.y; li = base + k + 1; }
                if (q.z > lv) { lv = q.z; li = base + k + 2; }
                if (q.w > lv) { lv = q.w; li = base + k + 3; }
            }
        }
    }
}

// ---------------- merge 4x32 candidates -> global top-32 ----------------
__global__ __launch_bounds__(128) void awm_merge_kernel(
    const float* __restrict__ cand_val, const int* __restrict__ cand_idx,
    int* __restrict__ topidx) {
    int r = blockIdx.x;
    int tid = threadIdx.x;  // 128
    __shared__ float wv_s[2];
    __shared__ int wi_s[2];
    __shared__ int win_s;
    float v0 = cand_val[r * 128 + tid];
    int gi0 = cand_idx[r * 128 + tid];
    int wid = tid >> 6, lane = tid & 63;
    for (int it = 0; it < TOPK_; ++it) {
        float v = v0; int gi = gi0;
#pragma unroll
        for (int off = 32; off > 0; off >>= 1) {
            float ov = __shfl_xor(v, off);
            int oi = __shfl_xor(gi, off);
            if (ov > v || (ov == v && (unsigned)oi < (unsigned)gi)) { v = ov; gi = oi; }
        }
        if (lane == 0) { wv_s[wid] = v; wi_s[wid] = gi; }
        __syncthreads();
        if (tid == 0) {
            float bv = wv_s[0]; int bi = wi_s[0];
            if (wv_s[1] > bv || (wv_s[1] == bv && (unsigned)wi_s[1] < (unsigned)bi)) { bv = wv_s[1]; bi = wi_s[1]; }
            topidx[r * TOPK_ + it] = bi;
            win_s = bi;
        }
        __syncthreads();
        if (gi0 == win_s) v0 = -INFINITY;
    }
}

// ---------------- hidden proj GEMM: hq = q@W1q + bs1 (y=0), hkc = k@W1k (y=1) ----------------
// M = B*H*T = 4096 rows (row gather from (b,t,h)-layout), K=64, N=128
__global__ __launch_bounds__(256) void awm_hid_kernel(
    const float* __restrict__ q_flat, const float* __restrict__ k_flat,
    const float* __restrict__ Ws1, const float* __restrict__ bs1,
    float* __restrict__ hq, float* __restrict__ hkc) {
    int isK = blockIdx.y;
    int bm = blockIdx.x * 64;
    int tid = threadIdx.x;
    __shared__ float As[64][68];     // [k][m]
    __shared__ float Ws_s[64][132];  // [k][f]
    const float* src = isK ? k_flat : q_flat;
    const float* W = Ws1 + (isK ? (size_t)DH_ * HID_ : 0);
    {
        int m = tid >> 2, kq = (tid & 3) * 16;
        int rho = bm + m;
        int bh = rho >> 8, t = rho & 255;
        int b = bh >> 3, h = bh & 7;
        const float* sp = src + (size_t)(b * T_ + t) * HD_ + h * DH_ + kq;
#pragma unroll
        for (int i = 0; i < 16; i += 4) {
            float4 a = *(const float4*)(sp + i);
            As[kq+i+0][m] = a.x; As[kq+i+1][m] = a.y; As[kq+i+2][m] = a.z; As[kq+i+3][m] = a.w;
        }
    }
    for (int i = tid; i < 64 * HID_ / 4; i += 256) {
        int k = (i * 4) >> 7, f = (i * 4) & 127;
        *(float4*)&Ws_s[k][f] = *(const float4*)&W[(size_t)k * HID_ + f];
    }
    __syncthreads();
    int tm = (tid >> 4) * 4, tn = (tid & 15) * 8;
    float acc[4][8] = {};
#pragma unroll 8
    for (int k = 0; k < DH_; ++k) {
        float4 a4 = *(const float4*)&As[k][tm];
        float4 b0 = *(const float4*)&Ws_s[k][tn];
        float4 b1 = *(const float4*)&Ws_s[k][tn + 4];
        float av[4] = {a4.x, a4.y, a4.z, a4.w};
        float bv[8] = {b0.x, b0.y, b0.z, b0.w, b1.x, b1.y, b1.z, b1.w};
#pragma unroll
        for (int x = 0; x < 4; ++x)
#pragma unroll
            for (int y = 0; y < 8; ++y) acc[x][y] += av[x] * bv[y];
    }
    float* out = isK ? hkc : hq;
#pragma unroll
    for (int x = 0; x < 4; ++x) {
        int rho = bm + tm + x;
        float vv[8];
#pragma unroll
        for (int y = 0; y < 8; ++y)
            vv[y] = acc[x][y] + (isK ? 0.f : bs1[tn + y]);
        float4 r0, r1;
        r0.x = vv[0]; r0.y = vv[1]; r0.z = vv[2]; r0.w = vv[3];
        r1.x = vv[4]; r1.y = vv[5]; r1.z = vv[6]; r1.w = vv[7];
        float* op = out + (size_t)rho * HID_ + tn;
        *(float4*)op = r0; *(float4*)(op + 4) = r1;
    }
}

// ---------------- fused: hk_mem + mem scores, one block per (b,t); heads share keys ----------------
// smem_out[(b*H+h)*T + t][j] = sum_f relu(hq + hkm) * Ws2   (bs2 dropped: cancels in softmax)
__global__ __launch_bounds__(256) void awm_smem_kernel(
    const float* __restrict__ hq, const float* __restrict__ mkeys,
    const int* __restrict__ topidx, const float* __restrict__ Ws1,
    const float* __restrict__ Ws2, float* __restrict__ smem_out) {
    int bt = blockIdx.x;  // b*T + t
    int b = bt >> 8, t = bt & 255;
    int tid = threadIdx.x;
    __shared__ float W1k_s[32][132];   // k-chunk of W1k [k][f]
    __shared__ float mk_s[64][36];     // [k][j]
    __shared__ float hkm_s[32][133];   // [j][f], stride 133 -> conflict-free column reads
    __shared__ float hq_s[8][132];     // [h][f]
    __shared__ float w2_s[HID_];
    __shared__ int key_s[TOPK_];
    {
        int h = tid >> 5, fq = (tid & 31) * 4;
        *(float4*)&hq_s[h][fq] =
            *(const float4*)&hq[((size_t)(b * H_ + h) * T_ + t) * HID_ + fq];
    }
    if (tid < HID_) w2_s[tid] = Ws2[tid];
    if (tid < TOPK_) key_s[tid] = topidx[bt * TOPK_ + tid];
    __syncthreads();
    {
        int j = tid >> 3, kq = (tid & 7) * 8;
        const float* sp = mkeys + (size_t)key_s[j] * DH_ + kq;
        float4 a = *(const float4*)sp;
        float4 c = *(const float4*)(sp + 4);
        mk_s[kq+0][j] = a.x; mk_s[kq+1][j] = a.y; mk_s[kq+2][j] = a.z; mk_s[kq+3][j] = a.w;
        mk_s[kq+4][j] = c.x; mk_s[kq+5][j] = c.y; mk_s[kq+6][j] = c.z; mk_s[kq+7][j] = c.w;
    }
    int j0 = (tid >> 5) * 4, f0 = (tid & 31) * 4;
    float acc[4][4] = {};
    for (int kc = 0; kc < 2; ++kc) {
        __syncthreads();
        for (int i = tid; i < 32 * HID_ / 4; i += 256) {
            int k = (i * 4) >> 7, f = (i * 4) & 127;
            *(float4*)&W1k_s[k][f] =
                *(const float4*)&Ws1[(size_t)(DH_ + kc * 32 + k) * HID_ + f];
        }
        __syncthreads();
#pragma unroll 8
        for (int k = 0; k < 32; ++k) {
            float4 a4 = *(const float4*)&mk_s[kc * 32 + k][j0];
            float4 b4 = *(const float4*)&W1k_s[k][f0];
            float av[4] = {a4.x, a4.y, a4.z, a4.w};
            float bv[4] = {b4.x, b4.y, b4.z, b4.w};
#pragma unroll
            for (int x = 0; x < 4; ++x)
#pragma unroll
                for (int y = 0; y < 4; ++y) acc[x][y] += av[x] * bv[y];
        }
    }
#pragma unroll
    for (int x = 0; x < 4; ++x)
#pragma unroll
        for (int y = 0; y < 4; ++y) hkm_s[j0 + x][f0 + y] = acc[x][y];
    __syncthreads();
    int h = tid >> 5, j = tid & 31;
    float sacc = 0.f;
#pragma unroll 8
    for (int f = 0; f < HID_; ++f) {
        float u = hq_s[h][f] + hkm_s[j][f];
        sacc += fmaxf(u, 0.f) * w2_s[f];
    }
    smem_out[((size_t)(b * H_ + h) * T_ + t) * TOPK_ + j] = sacc;
}

// ---------------- fused ctx scores + softmax + PV + gate; block = (b,h, 16-t tile) ----------------
__global__ __launch_bounds__(256) void awm_attn2_kernel(
    const float* __restrict__ hq, const float* __restrict__ hkc,
    const float* __restrict__ smem_in, const float* __restrict__ v_flat,
    const float* __restrict__ mem_values, const int* __restrict__ topidx,
    const float* __restrict__ Ws2, const float* __restrict__ gates,
    float* __restrict__ outg) {
    int tb = blockIdx.x;       // t-tile index (0..15)
    int bh = blockIdx.y;       // b*H + h
    int b = bh >> 3, h = bh & 7;
    int tbase = tb * TT_;
    int tid = threadIdx.x;
    __shared__ float hq_s[HID_][TT_ + 2];        // [f][t]
    __shared__ float hk_s[32][132];              // [f-chunk][s]
    __shared__ float sc_T[T_ + TOPK_][TT_ + 2];  // [s][t]
    __shared__ float w2_s[HID_];
    __shared__ int idx_s[TT_][TOPK_];
    // stage hq tile transposed
    {
        int t = tid >> 4, fq = (tid & 15) * 8;
        const float* sp = hq + ((size_t)bh * T_ + tbase + t) * HID_ + fq;
        float4 a = *(const float4*)sp;
        float4 c = *(const float4*)(sp + 4);
        hq_s[fq+0][t] = a.x; hq_s[fq+1][t] = a.y; hq_s[fq+2][t] = a.z; hq_s[fq+3][t] = a.w;
        hq_s[fq+4][t] = c.x; hq_s[fq+5][t] = c.y; hq_s[fq+6][t] = c.z; hq_s[fq+7][t] = c.w;
    }
    if (tid < HID_) w2_s[tid] = Ws2[tid];
    for (int i = tid; i < TT_ * TOPK_; i += 256) {
        int t = i >> 5, j = i & 31;
        sc_T[T_ + j][t] = smem_in[((size_t)bh * T_ + tbase + t) * TOPK_ + j];
        idx_s[t][j] = topidx[((size_t)b * T_ + tbase + t) * TOPK_ + j];
    }
    // ctx scores: 16t x 128s tiles, f in chunks of 32
    int t0 = (tid >> 5) * 2, s0 = (tid & 31) * 4;
    for (int sb = 0; sb < 2; ++sb) {
        float acc[2][4] = {};
        for (int fc = 0; fc < 4; ++fc) {
            __syncthreads();   // previous hk_s users done
            {
                int f4 = (tid & 7) * 4;
                int srow = tid >> 3;
#pragma unroll
                for (int p = 0; p < 4; ++p) {
                    int s = srow + p * 32;
                    float4 a = *(const float4*)&hkc[((size_t)bh * T_ + sb * 128 + s) * HID_ + fc * 32 + f4];
                    hk_s[f4+0][s] = a.x; hk_s[f4+1][s] = a.y; hk_s[f4+2][s] = a.z; hk_s[f4+3][s] = a.w;
                }
            }
            __syncthreads();
#pragma unroll 8
            for (int f = 0; f < 32; ++f) {
                float2 av2 = *(const float2*)&hq_s[fc * 32 + f][t0];
                float4 bv4 = *(const float4*)&hk_s[f][s0];
                float w2f = w2_s[fc * 32 + f];
                float av[2] = {av2.x, av2.y};
                float bv[4] = {bv4.x, bv4.y, bv4.z, bv4.w};
#pragma unroll
                for (int x = 0; x < 2; ++x)
#pragma unroll
                    for (int y = 0; y < 4; ++y) {
                        float u = av[x] + bv[y];
                        acc[x][y] += fmaxf(u, 0.f) * w2f;
                    }
            }
        }
#pragma unroll
        for (int x = 0; x < 2; ++x)
#pragma unroll
            for (int y = 0; y < 4; ++y)
                sc_T[sb * 128 + s0 + y][t0 + x] = acc[x][y];
    }
    __syncthreads();
    // softmax over 288, 16 lanes per t row
    {
        int t = tid >> 4, l = tid & 15;
        float mx = -INFINITY;
        for (int s = l; s < T_ + TOPK_; s += 16) mx = fmaxf(mx, sc_T[s][t]);
#pragma unroll
        for (int off = 8; off > 0; off >>= 1) mx = fmaxf(mx, __shfl_xor(mx, off, 16));
        float sum = 0.f;
        for (int s = l; s < T_ + TOPK_; s += 16) {
            float e = expf(sc_T[s][t] - mx);
            sc_T[s][t] = e;
            sum += e;
        }
#pragma unroll
        for (int off = 8; off > 0; off >>= 1) sum += __shfl_xor(sum, off, 16);
        float inv = 1.f / sum;
        for (int s = l; s < T_ + TOPK_; s += 16) sc_T[s][t] *= inv;
    }
    __syncthreads();
    // PV + gate: thread = (2 t, 2 d)
    {
        int tp = (tid >> 5) * 2, dq = (tid & 31) * 2;
        float a00 = 0.f, a01 = 0.f, a10 = 0.f, a11 = 0.f;
        const float* vb = v_flat + (size_t)b * T_ * HD_ + h * DH_ + dq;
#pragma unroll 4
        for (int s = 0; s < T_; ++s) {
            float2 w = *(const float2*)&sc_T[s][tp];
            float2 vv = *(const float2*)&vb[(size_t)s * HD_];
            a00 += w.x * vv.x; a01 += w.x * vv.y;
            a10 += w.y * vv.x; a11 += w.y * vv.y;
        }
#pragma unroll 4
        for (int j = 0; j < TOPK_; ++j) {
            float2 w = *(const float2*)&sc_T[T_ + j][tp];
            float2 m0 = *(const float2*)&mem_values[(size_t)idx_s[tp][j] * DH_ + dq];
            float2 m1 = *(const float2*)&mem_values[(size_t)idx_s[tp + 1][j] * DH_ + dq];
            a00 += w.x * m0.x; a01 += w.x * m0.y;
            a10 += w.y * m1.x; a11 += w.y * m1.y;
        }
        float g0 = gates[(size_t)(b * T_ + tbase + tp) * H_ + h];
        float g1v = gates[(size_t)(b * T_ + tbase + tp + 1) * H_ + h];
        float* o0 = outg + (size_t)(b * T_ + tbase + tp) * HD_ + h * DH_ + dq;
        float* o1 = o0 + HD_;
        float2 r0, r1;
        r0.x = a00 * g0; r0.y = a01 * g0;
        r1.x = a10 * g1v; r1.y = a11 * g1v;
        *(float2*)o0 = r0;
        *(float2*)o1 = r1;
    }
}

extern "C" void kernel_launch(void* const* d_in, const int* in_sizes, int n_in,
                              void* d_out, int out_size, void* d_ws, size_t ws_size,
                              hipStream_t stream) {
    (void)in_sizes; (void)n_in; (void)out_size; (void)ws_size;
    const float* x    = (const float*)d_in[0];
    const float* Wq   = (const float*)d_in[1];
    const float* Wk   = (const float*)d_in[2];
    const float* Wv   = (const float*)d_in[3];
    const float* Wo   = (const float*)d_in[4];
    const float* Wg1  = (const float*)d_in[5];
    const float* bg1  = (const float*)d_in[6];
    const float* Wg2  = (const float*)d_in[7];
    const float* bg2  = (const float*)d_in[8];
    const float* Ws1  = (const float*)d_in[9];
    const float* bs1  = (const float*)d_in[10];
    const float* Ws2  = (const float*)d_in[11];
    const float* mk   = (const float*)d_in[13];
    const float* mv   = (const float*)d_in[14];
    float* y = (float*)d_out;

    float* w = (float*)d_ws;
    size_t off = 0;
    float* q_flat = w + off; off += (size_t)BT_ * HD_;
    float* k_flat = w + off; off += (size_t)BT_ * HD_;
    float* v_flat = w + off; off += (size_t)BT_ * HD_;
    float* g1     = w + off; off += (size_t)BT_ * GH_;
    float* gates  = w + off; off += (size_t)BT_ * H_;
    float* qm     = w + off; off += (size_t)BT_ * DH_;
    float* selc   = w + off; off += (size_t)BT_ * SELC_;
    float* cand_v = w + off; off += (size_t)BT_ * 128;
    int*   cand_i = (int*)(w + off); off += (size_t)BT_ * 128;
    int*   topidx = (int*)(w + off); off += (size_t)BT_ * TOPK_;
    float* hq     = w + off; off += (size_t)B_ * H_ * T_ * HID_;
    float* hkc    = w + off; off += (size_t)B_ * H_ * T_ * HID_;
    float* smemb  = w + off; off += (size_t)B_ * H_ * T_ * TOPK_;
    float* outg   = w + off; off += (size_t)BT_ * HD_;

    dim3 thr256(256);
    // QKV in one launch (grid.z selects W/C)
    awm_proj_kernel<<<dim3(HD_ / 64, BT_ / 64, 3), thr256, 0, stream>>>(
        x, Wq, Wk, Wv, nullptr, q_flat, k_flat, v_flat, BT_, HD_, DM_, 0);
    awm_proj_kernel<<<dim3(GH_ / 64, BT_ / 64, 1), thr256, 0, stream>>>(
        x, Wg1, nullptr, nullptr, bg1, g1, nullptr, nullptr, BT_, GH_, DM_, 1);
    awm_gates_kernel<<<dim3((BT_ * H_ + 255) / 256), thr256, 0, stream>>>(g1, Wg2, bg2, gates);
    awm_qmean_kernel<<<dim3((BT_ * DH_ + 255) / 256), thr256, 0, stream>>>(q_flat, qm);
    // sel + topk, chunked
    for (int c = 0; c < NCHUNK_; ++c) {
        awm_selgemm_kernel<<<dim3(SELC_ / 128, BT_ / 64), thr256, 0, stream>>>(qm, mk, selc, c * SELC_);
        awm_seltop_kernel<<<dim3(BT_), thr256, 0, stream>>>(selc, cand_v, cand_i, c);
    }
    awm_merge_kernel<<<dim3(BT_), dim3(128), 0, stream>>>(cand_v, cand_i, topidx);
    // hidden projections (hq + hkc as tiled GEMMs)
    awm_hid_kernel<<<dim3(B_ * H_ * T_ / 64, 2), thr256, 0, stream>>>(q_flat, k_flat, Ws1, bs1, hq, hkc);
    // fused hk_mem + mem scores
    awm_smem_kernel<<<dim3(BT_), thr256, 0, stream>>>(hq, mk, topidx, Ws1, Ws2, smemb);
    // fused ctx scores + softmax + PV + gating
    awm_attn2_kernel<<<dim3(T_ / TT_, B_ * H_), thr256, 0, stream>>>(
        hq, hkc, smemb, v_flat, mv, topidx, Ws2, gates, outg);
    // output projection
    awm_proj_kernel<<<dim3(DM_ / 64, BT_ / 64, 1), thr256, 0, stream>>>(
        outg, Wo, nullptr, nullptr, nullptr, y, nullptr, nullptr, BT_, DM_, HD_, 0);
}

// Round 2
// 258.994 us; speedup vs baseline: 3.8848x; 1.7015x over previous
//
#include <hip/hip_runtime.h>
#include <math.h>

#define B_ 2
#define T_ 256
#define DM_ 512
#define H_ 8
#define DH_ 64
#define HID_ 128
#define GH_ 64
#define NMEM_ 32768
#define TOPK_ 32
#define BT_ (B_*T_)      // 512
#define HD_ (H_*DH_)     // 512
#define SELC_ 8192
#define NCHUNK_ (NMEM_/SELC_)  // 4
#define TT_ 8            // t-tile for fused attention

// ---------------- fused QKV + gelu-gate projections ----------------
// z=0..2: C = x @ W (N=512). z=3: g1 = gelu(x @ Wg1 + bg1), gates = sigmoid(g1 @ Wg2 + bg2)
__global__ __launch_bounds__(256) void awm_qkvg_kernel(
    const float* __restrict__ x,
    const float* __restrict__ Wq, const float* __restrict__ Wk, const float* __restrict__ Wv,
    const float* __restrict__ Wg1, const float* __restrict__ bg1,
    const float* __restrict__ Wg2, const float* __restrict__ bg2,
    float* __restrict__ q, float* __restrict__ k, float* __restrict__ v,
    float* __restrict__ gates) {
    int z = blockIdx.z;
    if (z == 3 && blockIdx.x != 0) return;
    const float* W = (z == 0) ? Wq : (z == 1) ? Wk : (z == 2) ? Wv : Wg1;
    float* C = (z == 0) ? q : (z == 1) ? k : v;
    const int N = (z == 3) ? GH_ : HD_;
    __shared__ float As[32][34];
    __shared__ float Bs[32][68];
    int bm = blockIdx.y * 32, bn = blockIdx.x * 64;
    int tid = threadIdx.x;
    int tm = (tid >> 4) * 2, tn = (tid & 15) * 4;
    float acc[2][4] = {};
    for (int k0 = 0; k0 < DM_; k0 += 32) {
        {
            int m = tid >> 3, kk = (tid & 7) * 4;
            float4 a = *(const float4*)&x[(size_t)(bm + m) * DM_ + k0 + kk];
            As[kk+0][m] = a.x; As[kk+1][m] = a.y; As[kk+2][m] = a.z; As[kk+3][m] = a.w;
#pragma unroll
            for (int p = 0; p < 2; ++p) {
                int idx = tid * 4 + p * 1024;
                int kb = idx >> 6, n = idx & 63;
                *(float4*)&Bs[kb][n] = *(const float4*)&W[(size_t)(k0 + kb) * N + bn + n];
            }
        }
        __syncthreads();
#pragma unroll
        for (int kk = 0; kk < 32; ++kk) {
            float2 a2 = *(const float2*)&As[kk][tm];
            float4 b4 = *(const float4*)&Bs[kk][tn];
            acc[0][0] += a2.x * b4.x; acc[0][1] += a2.x * b4.y;
            acc[0][2] += a2.x * b4.z; acc[0][3] += a2.x * b4.w;
            acc[1][0] += a2.y * b4.x; acc[1][1] += a2.y * b4.y;
            acc[1][2] += a2.y * b4.z; acc[1][3] += a2.y * b4.w;
        }
        __syncthreads();
    }
    if (z < 3) {
#pragma unroll
        for (int xr = 0; xr < 2; ++xr) {
            float4 r; r.x = acc[xr][0]; r.y = acc[xr][1]; r.z = acc[xr][2]; r.w = acc[xr][3];
            *(float4*)&C[(size_t)(bm + tm + xr) * HD_ + bn + tn] = r;
        }
    } else {
        // gelu epilogue into Bs (reused as g1_s[32 rows][68])
#pragma unroll
        for (int xr = 0; xr < 2; ++xr)
#pragma unroll
            for (int y = 0; y < 4; ++y) {
                float vv = acc[xr][y] + bg1[tn + y];
                float u = 0.7978845608028654f * (vv + 0.044715f * vv * vv * vv);
                Bs[tm + xr][tn + y] = 0.5f * vv * (1.f + tanhf(u));
            }
        float* wg = &As[0][0];   // 512 floats of Wg2 fit in As (1088)
        for (int i = tid; i < GH_ * H_; i += 256) wg[i] = Wg2[i];
        __syncthreads();
        int r = tid >> 3, hh = tid & 7;
        float acg = bg2[hh];
#pragma unroll
        for (int j = 0; j < GH_; ++j) acg += Bs[r][j] * wg[j * H_ + hh];
        gates[(size_t)(bm + r) * H_ + hh] = 1.f / (1.f + expf(-acg));
    }
}

// ---------------- output projection: y = outg @ Wo ----------------
__global__ __launch_bounds__(256) void awm_out_kernel(
    const float* __restrict__ A, const float* __restrict__ W, float* __restrict__ C) {
    __shared__ float As[32][34];
    __shared__ float Bs[32][68];
    int bm = blockIdx.y * 32, bn = blockIdx.x * 64;
    int tid = threadIdx.x;
    int tm = (tid >> 4) * 2, tn = (tid & 15) * 4;
    float acc[2][4] = {};
    for (int k0 = 0; k0 < HD_; k0 += 32) {
        {
            int m = tid >> 3, kk = (tid & 7) * 4;
            float4 a = *(const float4*)&A[(size_t)(bm + m) * HD_ + k0 + kk];
            As[kk+0][m] = a.x; As[kk+1][m] = a.y; As[kk+2][m] = a.z; As[kk+3][m] = a.w;
#pragma unroll
            for (int p = 0; p < 2; ++p) {
                int idx = tid * 4 + p * 1024;
                int kb = idx >> 6, n = idx & 63;
                *(float4*)&Bs[kb][n] = *(const float4*)&W[(size_t)(k0 + kb) * DM_ + bn + n];
            }
        }
        __syncthreads();
#pragma unroll
        for (int kk = 0; kk < 32; ++kk) {
            float2 a2 = *(const float2*)&As[kk][tm];
            float4 b4 = *(const float4*)&Bs[kk][tn];
            acc[0][0] += a2.x * b4.x; acc[0][1] += a2.x * b4.y;
            acc[0][2] += a2.x * b4.z; acc[0][3] += a2.x * b4.w;
            acc[1][0] += a2.y * b4.x; acc[1][1] += a2.y * b4.y;
            acc[1][2] += a2.y * b4.z; acc[1][3] += a2.y * b4.w;
        }
        __syncthreads();
    }
#pragma unroll
    for (int xr = 0; xr < 2; ++xr) {
        float4 r; r.x = acc[xr][0]; r.y = acc[xr][1]; r.z = acc[xr][2]; r.w = acc[xr][3];
        *(float4*)&C[(size_t)(bm + tm + xr) * DM_ + bn + tn] = r;
    }
}

// ---------------- q_for_mem: mean over heads ----------------
__global__ void awm_qmean_kernel(const float* __restrict__ q_flat, float* __restrict__ qm) {
    int i = blockIdx.x * 256 + threadIdx.x;  // r*DH + d
    if (i >= BT_ * DH_) return;
    int r = i / DH_, d = i % DH_;
    float acc = 0.f;
#pragma unroll
    for (int h = 0; h < H_; ++h) acc += q_flat[r * HD_ + h * DH_ + d];
    qm[i] = acc * 0.125f;
}

// ---------------- sel GEMM: selc[r][col] = qm[r] . mem_keys[chunk0+col] ----------------
__global__ __launch_bounds__(256) void awm_selgemm_kernel(
    const float* __restrict__ qm, const float* __restrict__ mkeys,
    float* __restrict__ selc, int chunk0, int ld) {
    __shared__ float Qs[64][68];    // [d][m]
    __shared__ float Ks[64][132];   // [d][n]
    int bn = blockIdx.x * 128;
    int bm = blockIdx.y * 64;
    int tid = threadIdx.x;
#pragma unroll
    for (int p = 0; p < 4; ++p) {
        int i4 = tid * 4 + p * 1024;
        int m = i4 >> 6, d = i4 & 63;
        float4 a = *(const float4*)&qm[(size_t)(bm + m) * DH_ + d];
        Qs[d+0][m] = a.x; Qs[d+1][m] = a.y; Qs[d+2][m] = a.z; Qs[d+3][m] = a.w;
    }
#pragma unroll
    for (int p = 0; p < 8; ++p) {
        int i4 = tid * 4 + p * 1024;
        int n = i4 >> 6, d = i4 & 63;
        float4 a = *(const float4*)&mkeys[(size_t)(chunk0 + bn + n) * DH_ + d];
        Ks[d+0][n] = a.x; Ks[d+1][n] = a.y; Ks[d+2][n] = a.z; Ks[d+3][n] = a.w;
    }
    __syncthreads();
    int tm = (tid >> 4) * 4;
    int tn = (tid & 15) * 8;
    float acc[4][8] = {};
#pragma unroll 8
    for (int d = 0; d < 64; ++d) {
        float4 a4 = *(const float4*)&Qs[d][tm];
        float4 b0 = *(const float4*)&Ks[d][tn];
        float4 b1 = *(const float4*)&Ks[d][tn + 4];
        float av[4] = {a4.x, a4.y, a4.z, a4.w};
        float bv[8] = {b0.x, b0.y, b0.z, b0.w, b1.x, b1.y, b1.z, b1.w};
#pragma unroll
        for (int x = 0; x < 4; ++x)
#pragma unroll
            for (int y = 0; y < 8; ++y) acc[x][y] += av[x] * bv[y];
    }
#pragma unroll
    for (int x = 0; x < 4; ++x) {
        float* cp = &selc[(size_t)(bm + tm + x) * ld + bn + tn];
        float4 r0, r1;
        r0.x = acc[x][0]; r0.y = acc[x][1]; r0.z = acc[x][2]; r0.w = acc[x][3];
        r1.x = acc[x][4]; r1.y = acc[x][5]; r1.z = acc[x][6]; r1.w = acc[x][7];
        *(float4*)cp = r0; *(float4*)(cp + 4) = r1;
    }
}

// ---------------- per-chunk top-32: wave-local, barrier-free extraction ----------------
// Each wave owns 2048 elements, emits its own sorted top-32 -> 128 candidates per (r,chunk).
__global__ __launch_bounds__(256) void awm_seltop_kernel(
    const float* __restrict__ selc, int ld, int chunk_arg,
    float* __restrict__ cand_val, int* __restrict__ cand_idx) {
    int r = blockIdx.x;
    int chunk = (chunk_arg >= 0) ? chunk_arg : (int)blockIdx.y;
    int col0 = (ld == NMEM_) ? chunk * SELC_ : 0;
    int tid = threadIdx.x;
    __shared__ float sv[SELC_];
    const float* src = selc + (size_t)r * ld + col0;
    for (int p = 0; p < 8; ++p) {
        int i = (tid + p * 256) * 4;
        *(float4*)&sv[i] = *(const float4*)&src[i];
    }
    __syncthreads();
    int w = tid >> 6, lane = tid & 63;
    int base = tid * 32;
    float lv = -INFINITY; int li = 0x7fffffff;
#pragma unroll
    for (int k = 0; k < 32; k += 4) {
        float4 qv = *(const float4*)&sv[base + k];
        if (qv.x > lv) { lv = qv.x; li = base + k; }
        if (qv.y > lv) { lv = qv.y; li = base + k + 1; }
        if (qv.z > lv) { lv = qv.z; li = base + k + 2; }
        if (qv.w > lv) { lv = qv.w; li = base + k + 3; }
    }
    float* cv = cand_val + (size_t)r * 512 + chunk * 128 + w * 32;
    int* ci = cand_idx + (size_t)r * 512 + chunk * 128 + w * 32;
    for (int it = 0; it < TOPK_; ++it) {
        float v = lv; int ix = li;
#pragma unroll
        for (int off = 32; off > 0; off >>= 1) {
            float ov = __shfl_xor(v, off);
            int oi = __shfl_xor(ix, off);
            if (ov > v || (ov == v && oi < ix)) { v = ov; ix = oi; }
        }
        if (lane == 0) { cv[it] = v; ci[it] = chunk * SELC_ + ix; }
        if (ix >= base && ix < base + 32) {   // owner invalidates + rescans its 32
            sv[ix] = -INFINITY;
            lv = -INFINITY; li = 0x7fffffff;
#pragma unroll
            for (int k = 0; k < 32; k += 4) {
                float4 qv = *(const float4*)&sv[base + k];
                if (qv.x > lv) { lv = qv.x; li = base + k; }
                if (qv.y > lv) { lv = qv.y; li = base + k + 1; }
                if (qv.z > lv) { lv = qv.z; li = base + k + 2; }
                if (qv.w > lv) { lv = qv.w; li = base + k + 3; }
            }
        }
    }
}

// ---------------- merge 512 candidates -> global top-32 (2 barriers total) ----------------
__global__ __launch_bounds__(256) void awm_merge_kernel(
    const float* __restrict__ cand_val, const int* __restrict__ cand_idx,
    int* __restrict__ topidx) {
    int r = blockIdx.x;
    int tid = threadIdx.x;
    __shared__ float sval[128];
    __shared__ int sidx[128];
    int w = tid >> 6, lane = tid & 63;
    float v0 = cand_val[(size_t)r * 512 + tid];
    float v1 = cand_val[(size_t)r * 512 + 256 + tid];
    int i0 = cand_idx[(size_t)r * 512 + tid];
    int i1 = cand_idx[(size_t)r * 512 + 256 + tid];
    // phase 1: each wave extracts top-32 of its 128 candidates (barrier-free)
    for (int it = 0; it < TOPK_; ++it) {
        float v; int ix;
        if (v0 > v1 || (v0 == v1 && i0 < i1)) { v = v0; ix = i0; } else { v = v1; ix = i1; }
#pragma unroll
        for (int off = 32; off > 0; off >>= 1) {
            float ov = __shfl_xor(v, off);
            int oi = __shfl_xor(ix, off);
            if (ov > v || (ov == v && oi < ix)) { v = ov; ix = oi; }
        }
        if (lane == 0) { sval[w * 32 + it] = v; sidx[w * 32 + it] = ix; }
        if (ix == i0) v0 = -INFINITY;
        else if (ix == i1) v1 = -INFINITY;
    }
    __syncthreads();
    // phase 2: wave 0 merges the 128 survivors
    if (w == 0) {
        float a0 = sval[lane], a1 = sval[64 + lane];
        int j0 = sidx[lane], j1 = sidx[64 + lane];
        for (int it = 0; it < TOPK_; ++it) {
            float v; int ix;
            if (a0 > a1 || (a0 == a1 && j0 < j1)) { v = a0; ix = j0; } else { v = a1; ix = j1; }
#pragma unroll
            for (int off = 32; off > 0; off >>= 1) {
                float ov = __shfl_xor(v, off);
                int oi = __shfl_xor(ix, off);
                if (ov > v || (ov == v && oi < ix)) { v = ov; ix = oi; }
            }
            if (lane == 0) topidx[r * TOPK_ + it] = ix;
            if (ix == j0) a0 = -INFINITY;
            else if (ix == j1) a1 = -INFINITY;
        }
    }
}

// ---------------- hidden proj GEMM: hq = q@W1q + bs1 (y=0), hkc = k@W1k (y=1) ----------------
__global__ __launch_bounds__(256) void awm_hid_kernel(
    const float* __restrict__ q_flat, const float* __restrict__ k_flat,
    const float* __restrict__ Ws1, const float* __restrict__ bs1,
    float* __restrict__ hq, float* __restrict__ hkc) {
    int isK = blockIdx.y;
    int bm = blockIdx.x * 32;
    int tid = threadIdx.x;
    __shared__ float As[64][34];     // [k][m]
    __shared__ float Ws_s[64][132];  // [k][f]
    const float* src = isK ? k_flat : q_flat;
    const float* W = Ws1 + (isK ? (size_t)DH_ * HID_ : 0);
    {
        int m = tid >> 3, kq = (tid & 7) * 8;
        int rho = bm + m;
        int bh = rho >> 8, t = rho & 255;
        int b = bh >> 3, h = bh & 7;
        const float* sp = src + (size_t)(b * T_ + t) * HD_ + h * DH_ + kq;
        float4 a = *(const float4*)sp;
        float4 c = *(const float4*)(sp + 4);
        As[kq+0][m] = a.x; As[kq+1][m] = a.y; As[kq+2][m] = a.z; As[kq+3][m] = a.w;
        As[kq+4][m] = c.x; As[kq+5][m] = c.y; As[kq+6][m] = c.z; As[kq+7][m] = c.w;
    }
    for (int i = tid; i < 64 * HID_ / 4; i += 256) {
        int k = (i * 4) >> 7, f = (i * 4) & 127;
        *(float4*)&Ws_s[k][f] = *(const float4*)&W[(size_t)k * HID_ + f];
    }
    __syncthreads();
    int tm = (tid >> 4) * 2, tn = (tid & 15) * 8;
    float acc[2][8] = {};
#pragma unroll 8
    for (int k = 0; k < DH_; ++k) {
        float2 a2 = *(const float2*)&As[k][tm];
        float4 b0 = *(const float4*)&Ws_s[k][tn];
        float4 b1 = *(const float4*)&Ws_s[k][tn + 4];
        float av[2] = {a2.x, a2.y};
        float bv[8] = {b0.x, b0.y, b0.z, b0.w, b1.x, b1.y, b1.z, b1.w};
#pragma unroll
        for (int x = 0; x < 2; ++x)
#pragma unroll
            for (int y = 0; y < 8; ++y) acc[x][y] += av[x] * bv[y];
    }
    float* out = isK ? hkc : hq;
#pragma unroll
    for (int x = 0; x < 2; ++x) {
        int rho = bm + tm + x;
        float vv[8];
#pragma unroll
        for (int y = 0; y < 8; ++y)
            vv[y] = acc[x][y] + (isK ? 0.f : bs1[tn + y]);
        float4 r0, r1;
        r0.x = vv[0]; r0.y = vv[1]; r0.z = vv[2]; r0.w = vv[3];
        r1.x = vv[4]; r1.y = vv[5]; r1.z = vv[6]; r1.w = vv[7];
        float* op = out + (size_t)rho * HID_ + tn;
        *(float4*)op = r0; *(float4*)(op + 4) = r1;
    }
}

// ---------------- fused: hk_mem + mem scores, one block per (b,t); heads share keys ----------------
__global__ __launch_bounds__(256) void awm_smem_kernel(
    const float* __restrict__ hq, const float* __restrict__ mkeys,
    const int* __restrict__ topidx, const float* __restrict__ Ws1,
    const float* __restrict__ Ws2, float* __restrict__ smem_out) {
    int bt = blockIdx.x;  // b*T + t
    int b = bt >> 8, t = bt & 255;
    int tid = threadIdx.x;
    __shared__ float W1k_s[32][132];
    __shared__ float mk_s[64][36];
    __shared__ float hkm_s[32][133];
    __shared__ float hq_s[8][132];
    __shared__ float w2_s[HID_];
    __shared__ int key_s[TOPK_];
    {
        int h = tid >> 5, fq = (tid & 31) * 4;
        *(float4*)&hq_s[h][fq] =
            *(const float4*)&hq[((size_t)(b * H_ + h) * T_ + t) * HID_ + fq];
    }
    if (tid < HID_) w2_s[tid] = Ws2[tid];
    if (tid < TOPK_) key_s[tid] = topidx[bt * TOPK_ + tid];
    __syncthreads();
    {
        int j = tid >> 3, kq = (tid & 7) * 8;
        const float* sp = mkeys + (size_t)key_s[j] * DH_ + kq;
        float4 a = *(const float4*)sp;
        float4 c = *(const float4*)(sp + 4);
        mk_s[kq+0][j] = a.x; mk_s[kq+1][j] = a.y; mk_s[kq+2][j] = a.z; mk_s[kq+3][j] = a.w;
        mk_s[kq+4][j] = c.x; mk_s[kq+5][j] = c.y; mk_s[kq+6][j] = c.z; mk_s[kq+7][j] = c.w;
    }
    int j0 = (tid >> 5) * 4, f0 = (tid & 31) * 4;
    float acc[4][4] = {};
    for (int kc = 0; kc < 2; ++kc) {
        __syncthreads();
        for (int i = tid; i < 32 * HID_ / 4; i += 256) {
            int k = (i * 4) >> 7, f = (i * 4) & 127;
            *(float4*)&W1k_s[k][f] =
                *(const float4*)&Ws1[(size_t)(DH_ + kc * 32 + k) * HID_ + f];
        }
        __syncthreads();
#pragma unroll 8
        for (int k = 0; k < 32; ++k) {
            float4 a4 = *(const float4*)&mk_s[kc * 32 + k][j0];
            float4 b4 = *(const float4*)&W1k_s[k][f0];
            float av[4] = {a4.x, a4.y, a4.z, a4.w};
            float bv[4] = {b4.x, b4.y, b4.z, b4.w};
#pragma unroll
            for (int x = 0; x < 4; ++x)
#pragma unroll
                for (int y = 0; y < 4; ++y) acc[x][y] += av[x] * bv[y];
        }
    }
#pragma unroll
    for (int x = 0; x < 4; ++x)
#pragma unroll
        for (int y = 0; y < 4; ++y) hkm_s[j0 + x][f0 + y] = acc[x][y];
    __syncthreads();
    int h = tid >> 5, j = tid & 31;
    float sacc = 0.f;
#pragma unroll 8
    for (int f = 0; f < HID_; ++f) {
        float u = hq_s[h][f] + hkm_s[j][f];
        sacc += fmaxf(u, 0.f) * w2_s[f];
    }
    smem_out[((size_t)(b * H_ + h) * T_ + t) * TOPK_ + j] = sacc;
}

// ---------------- fused ctx scores + softmax + PV + gate; block = (b,h, 8-t tile) ----------------
__global__ __launch_bounds__(256) void awm_attn2_kernel(
    const float* __restrict__ hq, const float* __restrict__ hkc,
    const float* __restrict__ smem_in, const float* __restrict__ v_flat,
    const float* __restrict__ mem_values, const int* __restrict__ topidx,
    const float* __restrict__ Ws2, const float* __restrict__ gates,
    float* __restrict__ outg) {
    int tb = blockIdx.x;       // t-tile index (0..31)
    int bh = blockIdx.y;       // b*H + h
    int b = bh >> 3, h = bh & 7;
    int tbase = tb * TT_;
    int tid = threadIdx.x;
    __shared__ float hq_s[HID_][TT_ + 2];   // [f][t]
    __shared__ float hk_s[32][260];         // [f-chunk][s]
    __shared__ float sc[TT_][292];          // [t][s] : 256 ctx + 32 mem
    __shared__ float w2_s[HID_];
    __shared__ int idx_s[TT_][TOPK_];
    // stage hq tile transposed: 8t x 128f, one float4/thread
    {
        int t = tid >> 5, fq = (tid & 31) * 4;
        float4 a = *(const float4*)&hq[((size_t)bh * T_ + tbase + t) * HID_ + fq];
        hq_s[fq+0][t] = a.x; hq_s[fq+1][t] = a.y; hq_s[fq+2][t] = a.z; hq_s[fq+3][t] = a.w;
    }
    if (tid < HID_) w2_s[tid] = Ws2[tid];
    // mem scores + gathered indices: 8x32, one per thread
    {
        int t = tid >> 5, j = tid & 31;
        sc[t][256 + j] = smem_in[((size_t)bh * T_ + tbase + t) * TOPK_ + j];
        idx_s[t][j] = topidx[((size_t)b * T_ + tbase + t) * TOPK_ + j];
    }
    // ctx scores: thread computes 2t x 4s over full s range
    int t0 = (tid >> 6) * 2, s0 = (tid & 63) * 4;
    float acc[2][4] = {};
    for (int fc = 0; fc < 4; ++fc) {
        __syncthreads();
        {   // stage hk_s[32f][256s]: 8 float4/thread
            int f4 = (tid & 7) * 4, sr = tid >> 3;
#pragma unroll
            for (int p = 0; p < 8; ++p) {
                int s = sr + p * 32;
                float4 a = *(const float4*)&hkc[((size_t)bh * T_ + s) * HID_ + fc * 32 + f4];
                hk_s[f4+0][s] = a.x; hk_s[f4+1][s] = a.y; hk_s[f4+2][s] = a.z; hk_s[f4+3][s] = a.w;
            }
        }
        __syncthreads();
#pragma unroll 8
        for (int f = 0; f < 32; ++f) {
            float2 a2 = *(const float2*)&hq_s[fc * 32 + f][t0];
            float4 b4 = *(const float4*)&hk_s[f][s0];
            float w2f = w2_s[fc * 32 + f];
            float av[2] = {a2.x, a2.y};
            float bv[4] = {b4.x, b4.y, b4.z, b4.w};
#pragma unroll
            for (int x = 0; x < 2; ++x)
#pragma unroll
                for (int y = 0; y < 4; ++y)
                    acc[x][y] += fmaxf(av[x] + bv[y], 0.f) * w2f;
        }
    }
    {
        float4 r0, r1;
        r0.x = acc[0][0]; r0.y = acc[0][1]; r0.z = acc[0][2]; r0.w = acc[0][3];
        r1.x = acc[1][0]; r1.y = acc[1][1]; r1.z = acc[1][2]; r1.w = acc[1][3];
        *(float4*)&sc[t0][s0] = r0;
        *(float4*)&sc[t0 + 1][s0] = r1;
    }
    __syncthreads();
    // softmax over 288: 32 lanes per t row
    {
        int t = tid >> 5, l = tid & 31;
        float mx = -INFINITY;
#pragma unroll
        for (int k = 0; k < 9; ++k) mx = fmaxf(mx, sc[t][l + 32 * k]);
#pragma unroll
        for (int off = 16; off > 0; off >>= 1) mx = fmaxf(mx, __shfl_xor(mx, off, 32));
        float sum = 0.f;
#pragma unroll
        for (int k = 0; k < 9; ++k) {
            float e = expf(sc[t][l + 32 * k] - mx);
            sc[t][l + 32 * k] = e;
            sum += e;
        }
#pragma unroll
        for (int off = 16; off > 0; off >>= 1) sum += __shfl_xor(sum, off, 32);
        float inv = 1.f / sum;
#pragma unroll
        for (int k = 0; k < 9; ++k) sc[t][l + 32 * k] *= inv;
    }
    __syncthreads();
    // PV + gate: group g handles t rows {2g, 2g+1}; lane l = d
    {
        int g = tid >> 6, l = tid & 63;
        int ta = 2 * g, tbb = 2 * g + 1;
        const float* vb = v_flat + (size_t)b * T_ * HD_ + h * DH_ + l;
        float a0 = 0.f, a1 = 0.f;
#pragma unroll 8
        for (int s = 0; s < T_; ++s) {
            float vv = vb[(size_t)s * HD_];
            a0 += sc[ta][s] * vv;
            a1 += sc[tbb][s] * vv;
        }
#pragma unroll 4
        for (int j = 0; j < TOPK_; ++j) {
            a0 += sc[ta][256 + j] * mem_values[(size_t)idx_s[ta][j] * DH_ + l];
            a1 += sc[tbb][256 + j] * mem_values[(size_t)idx_s[tbb][j] * DH_ + l];
        }
        float g0 = gates[(size_t)(b * T_ + tbase + ta) * H_ + h];
        float g1v = gates[(size_t)(b * T_ + tbase + tbb) * H_ + h];
        outg[(size_t)(b * T_ + tbase + ta) * HD_ + h * DH_ + l] = a0 * g0;
        outg[(size_t)(b * T_ + tbase + tbb) * HD_ + h * DH_ + l] = a1 * g1v;
    }
}

extern "C" void kernel_launch(void* const* d_in, const int* in_sizes, int n_in,
                              void* d_out, int out_size, void* d_ws, size_t ws_size,
                              hipStream_t stream) {
    (void)in_sizes; (void)n_in; (void)out_size;
    const float* x    = (const float*)d_in[0];
    const float* Wq   = (const float*)d_in[1];
    const float* Wk   = (const float*)d_in[2];
    const float* Wv   = (const float*)d_in[3];
    const float* Wo   = (const float*)d_in[4];
    const float* Wg1  = (const float*)d_in[5];
    const float* bg1  = (const float*)d_in[6];
    const float* Wg2  = (const float*)d_in[7];
    const float* bg2  = (const float*)d_in[8];
    const float* Ws1  = (const float*)d_in[9];
    const float* bs1  = (const float*)d_in[10];
    const float* Ws2  = (const float*)d_in[11];
    const float* mk   = (const float*)d_in[13];
    const float* mv   = (const float*)d_in[14];
    float* y = (float*)d_out;

    float* w = (float*)d_ws;
    size_t off = 0;
    float* q_flat = w + off; off += (size_t)BT_ * HD_;
    float* k_flat = w + off; off += (size_t)BT_ * HD_;
    float* v_flat = w + off; off += (size_t)BT_ * HD_;
    float* gates  = w + off; off += (size_t)BT_ * H_;
    float* qm     = w + off; off += (size_t)BT_ * DH_;
    float* hq     = w + off; off += (size_t)B_ * H_ * T_ * HID_;
    float* hkc    = w + off; off += (size_t)B_ * H_ * T_ * HID_;
    float* smemb  = w + off; off += (size_t)B_ * H_ * T_ * TOPK_;
    float* outg   = w + off; off += (size_t)BT_ * HD_;
    float* cand_v = w + off; off += (size_t)BT_ * 512;
    int*   cand_i = (int*)(w + off); off += (size_t)BT_ * 512;
    int*   topidx = (int*)(w + off); off += (size_t)BT_ * TOPK_;
    float* selc   = w + off;   // sized below: full = BT*NMEM, chunked = BT*SELC
    int fullw = (ws_size >= (off + (size_t)BT_ * NMEM_) * sizeof(float));

    dim3 thr256(256);
    // fused QKV + gelu/gates projections
    awm_qkvg_kernel<<<dim3(8, 16, 4), thr256, 0, stream>>>(
        x, Wq, Wk, Wv, Wg1, bg1, Wg2, bg2, q_flat, k_flat, v_flat, gates);
    awm_qmean_kernel<<<dim3((BT_ * DH_ + 255) / 256), thr256, 0, stream>>>(q_flat, qm);
    // selection
    if (fullw) {
        awm_selgemm_kernel<<<dim3(NMEM_ / 128, BT_ / 64), thr256, 0, stream>>>(
            qm, mk, selc, 0, NMEM_);
        awm_seltop_kernel<<<dim3(BT_, NCHUNK_), thr256, 0, stream>>>(
            selc, NMEM_, -1, cand_v, cand_i);
    } else {
        for (int c = 0; c < NCHUNK_; ++c) {
            awm_selgemm_kernel<<<dim3(SELC_ / 128, BT_ / 64), thr256, 0, stream>>>(
                qm, mk, selc, c * SELC_, SELC_);
            awm_seltop_kernel<<<dim3(BT_, 1), thr256, 0, stream>>>(
                selc, SELC_, c, cand_v, cand_i);
        }
    }
    awm_merge_kernel<<<dim3(BT_), thr256, 0, stream>>>(cand_v, cand_i, topidx);
    // additive-attention hidden projections
    awm_hid_kernel<<<dim3(B_ * H_ * T_ / 32, 2), thr256, 0, stream>>>(
        q_flat, k_flat, Ws1, bs1, hq, hkc);
    // fused hk_mem + mem scores
    awm_smem_kernel<<<dim3(BT_), thr256, 0, stream>>>(hq, mk, topidx, Ws1, Ws2, smemb);
    // fused ctx scores + softmax + PV + gating
    awm_attn2_kernel<<<dim3(T_ / TT_, B_ * H_), thr256, 0, stream>>>(
        hq, hkc, smemb, v_flat, mv, topidx, Ws2, gates, outg);
    // output projection
    awm_out_kernel<<<dim3(8, 16), thr256, 0, stream>>>(outg, Wo, y);
}